// Round 11
// baseline (276.086 us; speedup 1.0000x reference)
//
#include <hip/hip_runtime.h>
#include <stdint.h>

#define BN 4
#define CD 256
#define ND 4096
#define NK 32            // key-tile size in attention

typedef unsigned short u16;
typedef short bfrag __attribute__((ext_vector_type(8)));  // 8 bf16 = 4 VGPR
typedef float ffrag __attribute__((ext_vector_type(4)));  // MFMA C/D frag

__device__ __forceinline__ float bf2f(u16 u) {
  union { unsigned int i; float f; } v;
  v.i = ((unsigned int)u) << 16;
  return v.f;
}
__device__ __forceinline__ u16 f2bf(float f) {
  union { float f; unsigned int i; } v;
  v.f = f;
  return (u16)((v.i + 0x7FFFu + ((v.i >> 16) & 1u)) >> 16);  // RNE
}
// async global->LDS DMA, 16B per lane; LDS dest = wave-uniform base + lane*16
__device__ __forceinline__ void gload_lds(const u16* g, u16* l) {
  __builtin_amdgcn_global_load_lds(
      (const __attribute__((address_space(1))) void*)g,
      (__attribute__((address_space(3))) void*)l, 16, 0, 0);
}

// ---------- Q/K projection, direct from fp32, one block = 64 rows x 256 d --
// grid (256, 2). Input tile transposed+cast to LDS ONCE with conflict-free
// lane assignment (lane u writes rows {u,16+u,32+u,48+u} of column c);
// weights chunk-staged to LDS with inline fp32->bf16 cast.
__global__ __launch_bounds__(256, 2) void k_projQK(
    const float* __restrict__ x, const float* __restrict__ y,
    const float* __restrict__ Wq, const float* __restrict__ Wk,
    const float* __restrict__ bq, const float* __restrict__ bk,
    u16* __restrict__ Qb, u16* __restrict__ Kb) {
  __shared__ alignas(16) u16 As[64][264];  // As[n][c], input^T cast
  __shared__ alignas(16) u16 Ws[64][264];  // weight chunk [d_local][c]
  int m0 = blockIdx.x * 64;
  int z = blockIdx.y;
  int b = m0 >> 12, nsp = m0 & 4095;
  const float* src = (z ? y : x) + (size_t)b * CD * ND;
  const float* Wf = z ? Wk : Wq;
  const float* bias = z ? bk : bq;
  u16* Cd = (z ? Kb : Qb) + (size_t)m0 * CD;
  int t = threadIdx.x, w = t >> 6, l = t & 63;
  int lane16 = l & 15, quad = l >> 4;

  // A-staging, conflict-free: lane u = t&15 writes rows j*16+u of col c
  {
    int u = t & 15, grp = t >> 4;
#pragma unroll
    for (int it = 0; it < 16; ++it) {
      int c = it * 16 + grp;
      const float* col = src + (size_t)c * ND + nsp;
#pragma unroll
      for (int j = 0; j < 4; ++j)
        As[j * 16 + u][c] = f2bf(col[j * 16 + u]);
    }
  }
  __syncthreads();

  // A-frags in registers (rows w*16+lane16)
  bfrag af[8];
#pragma unroll
  for (int kc = 0; kc < 8; ++kc)
    af[kc] = *(const bfrag*)&As[w * 16 + lane16][kc * 32 + quad * 8];

  ffrag acc[16];
#pragma unroll
  for (int i = 0; i < 16; ++i) acc[i] = ffrag{0.f, 0.f, 0.f, 0.f};

#pragma unroll
  for (int c4 = 0; c4 < 4; ++c4) {  // 4 chunks of 64 d
    if (c4) __syncthreads();        // prior MFMA done reading Ws
#pragma unroll
    for (int it = 0; it < 16; ++it) {
      int idx = it * 256 + t;
      int row = idx >> 6, col = (idx & 63) * 4;
      float4 v = *(const float4*)(Wf + (size_t)(c4 * 64 + row) * CD + col);
      ushort4 o;
      o.x = f2bf(v.x); o.y = f2bf(v.y); o.z = f2bf(v.z); o.w = f2bf(v.w);
      *(ushort4*)&Ws[row][col] = o;
    }
    __syncthreads();
#pragma unroll
    for (int kc = 0; kc < 8; ++kc)
#pragma unroll
      for (int tt = 0; tt < 4; ++tt) {
        bfrag bfr = *(const bfrag*)&Ws[tt * 16 + lane16][kc * 32 + quad * 8];
        acc[c4 * 4 + tt] =
            __builtin_amdgcn_mfma_f32_16x16x32_bf16(af[kc], bfr, acc[c4 * 4 + tt], 0, 0, 0);
      }
  }
  // epilogue: row = w*16+quad*4+r, col = nt*16+lane16
#pragma unroll
  for (int nt = 0; nt < 16; ++nt) {
    int col = nt * 16 + lane16;
    float bcol = bias[col];
#pragma unroll
    for (int r = 0; r < 4; ++r) {
      int rowL = w * 16 + quad * 4 + r;
      Cd[(size_t)rowL * CD + col] = f2bf(acc[nt][r] + bcol);
    }
  }
}

// ---------- V projection, direct from fp32, out Vt[b][d][n] ----------
// grid (64, 4). y^T tile staged ONCE (conflict-free); Wv chunk-staged.
__global__ __launch_bounds__(256, 2) void k_projV(
    const float* __restrict__ y, const float* __restrict__ Wv,
    const float* __restrict__ bv, u16* __restrict__ Vb) {
  __shared__ alignas(16) u16 Bs[64][264];  // Bs[n][c] = y^T cast
  __shared__ alignas(16) u16 Ws[64][264];  // Wv chunk [d_local][c]
  int n0s = blockIdx.x * 64;
  int b = blockIdx.y;
  const float* src = y + (size_t)b * CD * ND;
  u16* Cd = Vb + (size_t)b * CD * ND;
  int t = threadIdx.x, w = t >> 6, l = t & 63;
  int lane16 = l & 15, quad = l >> 4;

  // B-staging, conflict-free lane assignment
  {
    int u = t & 15, grp = t >> 4;
#pragma unroll
    for (int it = 0; it < 16; ++it) {
      int c = it * 16 + grp;
      const float* col = src + (size_t)c * ND + n0s;
#pragma unroll
      for (int j = 0; j < 4; ++j)
        Bs[j * 16 + u][c] = f2bf(col[j * 16 + u]);
    }
  }
  __syncthreads();

  // B-frags in registers (n rows w*16+lane16)
  bfrag bfr8[8];
#pragma unroll
  for (int kc = 0; kc < 8; ++kc)
    bfr8[kc] = *(const bfrag*)&Bs[w * 16 + lane16][kc * 32 + quad * 8];

  ffrag o[16];
#pragma unroll
  for (int i = 0; i < 16; ++i) o[i] = ffrag{0.f, 0.f, 0.f, 0.f};

#pragma unroll
  for (int c4 = 0; c4 < 4; ++c4) {  // 4 chunks of 64 d
    if (c4) __syncthreads();
#pragma unroll
    for (int it = 0; it < 16; ++it) {
      int idx = it * 256 + t;
      int row = idx >> 6, col = (idx & 63) * 4;
      float4 v = *(const float4*)(Wv + (size_t)(c4 * 64 + row) * CD + col);
      ushort4 ov;
      ov.x = f2bf(v.x); ov.y = f2bf(v.y); ov.z = f2bf(v.z); ov.w = f2bf(v.w);
      *(ushort4*)&Ws[row][col] = ov;
    }
    __syncthreads();
#pragma unroll
    for (int kc = 0; kc < 8; ++kc)
#pragma unroll
      for (int mt = 0; mt < 4; ++mt) {
        bfrag af = *(const bfrag*)&Ws[mt * 16 + lane16][kc * 32 + quad * 8];
        o[c4 * 4 + mt] =
            __builtin_amdgcn_mfma_f32_16x16x32_bf16(af, bfr8[kc], o[c4 * 4 + mt], 0, 0, 0);
      }
  }
  // epilogue: d = c4*64 + mt*16 + quad*4 + r
#pragma unroll
  for (int i = 0; i < 16; ++i) {
    int c4 = i >> 2, mt = i & 3;
#pragma unroll
    for (int r = 0; r < 4; ++r) {
      int d = c4 * 64 + mt * 16 + quad * 4 + r;
      Cd[(size_t)d * ND + n0s + w * 16 + lane16] = f2bf(o[i][r] + bv[d]);
    }
  }
}

// ---------- flash attention + fused combine, split-K, async-DMA dbuf ------
// Q,K: [B*N][C]; Vt: [B][C][N]. 128 q-rows/block, 4 waves x 2 m-tiles.
// Last z-block per (q-tile,b) performs the combine+residual (atomic ticket).
union SmemU {
  struct {
    u16 Ks[2][NK][256];   // 32,768 B  chunk^=(row&7) swizzle
    u16 Vs[2][CD][NK];    // 32,768 B  chunk^=((d>>1)&3) swizzle
    u16 Ps[8][16][40];    // 10,240 B  wave-private P staging
  } a;                     // 75,776 B
  u16 ot[CD][136];         // 69,632 B  epilogue O^T staging
  float ls[128];           // combine-phase 1/l cache
};

template <int NS>
__global__ __launch_bounds__(256, 2) void k_attn(
    const u16* __restrict__ Q, const u16* __restrict__ K,
    const u16* __restrict__ Vt, u16* __restrict__ Opart,
    float* __restrict__ Lpart, int* __restrict__ cnt,
    const float* __restrict__ x, float* __restrict__ out) {
  constexpr int NIT = ND / NS / NK;
  __shared__ alignas(16) SmemU sm;
  __shared__ int lastFlag;
  int b = blockIdx.y, q0 = blockIdx.x * 128, z = blockIdx.z;
  int t = threadIdx.x, w = t >> 6, l = t & 63;
  int lane16 = l & 15, quad = l >> 4;
  const float scale = 0.0625f;  // 256^-0.5

  // Q frags: A-layout rows q0 + (w*2+mi)*16 + lane16
  bfrag qf[2][8];
#pragma unroll
  for (int mi = 0; mi < 2; ++mi) {
    const u16* Qrow =
        Q + ((size_t)b * ND + q0 + (w * 2 + mi) * 16 + lane16) * CD;
#pragma unroll
    for (int kc = 0; kc < 8; ++kc)
      qf[mi][kc] = *(const bfrag*)(Qrow + kc * 32 + quad * 8);
  }

  ffrag o[2][16];
#pragma unroll
  for (int mi = 0; mi < 2; ++mi)
#pragma unroll
    for (int i = 0; i < 16; ++i) o[mi][i] = ffrag{0.f, 0.f, 0.f, 0.f};
  float lsum[2][4] = {{0.f, 0.f, 0.f, 0.f}, {0.f, 0.f, 0.f, 0.f}};

  const u16* Kb = K + ((size_t)b * ND + z * (ND / NS)) * CD;
  const u16* Vb = Vt + (size_t)b * CD * ND + z * (ND / NS);

  auto stage = [&](int kt2) {
    int dbuf = kt2 & 1;
    const u16* Kt = Kb + (size_t)kt2 * NK * CD;
    const u16* Vtt = Vb + kt2 * NK;
#pragma unroll
    for (int p = 0; p < 4; ++p) {
      int r = p * 8 + w * 2 + (l >> 5);
      int j = (l & 31) ^ (r & 7);
      gload_lds(Kt + (size_t)r * CD + j * 8, &sm.a.Ks[dbuf][p * 8 + w * 2][0]);
    }
#pragma unroll
    for (int p = 0; p < 4; ++p) {
      int dd = p * 64 + w * 16 + (l >> 2);
      int j = (l & 3) ^ ((dd >> 1) & 3);
      gload_lds(Vtt + (size_t)dd * ND + j * 8, &sm.a.Vs[dbuf][p * 64 + w * 16][0]);
    }
  };

  stage(0);
  for (int kt = 0; kt < NIT; ++kt) {
    int dbuf = kt & 1;
    __syncthreads();  // drains DMA for buf dbuf; recycling of dbuf^1 is safe
    if (kt + 1 < NIT) stage(kt + 1);  // async into other buffer, no wait

    // S = Q K^T  (2 m-tiles x 2 key-tiles)
    ffrag s2[2][2];
#pragma unroll
    for (int mi = 0; mi < 2; ++mi)
#pragma unroll
      for (int tt = 0; tt < 2; ++tt) s2[mi][tt] = ffrag{0.f, 0.f, 0.f, 0.f};
#pragma unroll
    for (int kc = 0; kc < 8; ++kc) {
      bfrag kf0, kf1;
      {
        int r = lane16;
        int cp = (kc * 4 + quad) ^ (r & 7);
        kf0 = *(const bfrag*)&sm.a.Ks[dbuf][r][cp * 8];
        int r1 = 16 + lane16;
        int cp1 = (kc * 4 + quad) ^ (r1 & 7);
        kf1 = *(const bfrag*)&sm.a.Ks[dbuf][r1][cp1 * 8];
      }
#pragma unroll
      for (int mi = 0; mi < 2; ++mi) {
        s2[mi][0] = __builtin_amdgcn_mfma_f32_16x16x32_bf16(qf[mi][kc], kf0,
                                                            s2[mi][0], 0, 0, 0);
        s2[mi][1] = __builtin_amdgcn_mfma_f32_16x16x32_bf16(qf[mi][kc], kf1,
                                                            s2[mi][1], 0, 0, 0);
      }
    }

    // fixed-max softmax: p = exp(s*scale); lane-partial sums; P -> LDS
#pragma unroll
    for (int mi = 0; mi < 2; ++mi)
#pragma unroll
      for (int tt = 0; tt < 2; ++tt)
#pragma unroll
        for (int r = 0; r < 4; ++r) {
          float p = __expf(s2[mi][tt][r] * scale);
          lsum[mi][r] += p;
          sm.a.Ps[w * 2 + mi][quad * 4 + r][tt * 16 + lane16] = f2bf(p);
        }
    // wave-private Ps: in-wave LDS ordering suffices, no barrier
    bfrag pf0 = *(const bfrag*)&sm.a.Ps[w * 2 + 0][lane16][quad * 8];
    bfrag pf1 = *(const bfrag*)&sm.a.Ps[w * 2 + 1][lane16][quad * 8];

    // O += P V  (16 d-tiles, V-frag shared across both m-tiles)
#pragma unroll
    for (int dt = 0; dt < 16; ++dt) {
      int dd = dt * 16 + lane16;
      int cp = quad ^ ((dd >> 1) & 3);
      bfrag vf = *(const bfrag*)&sm.a.Vs[dbuf][dd][cp * 8];
      o[0][dt] = __builtin_amdgcn_mfma_f32_16x16x32_bf16(pf0, vf, o[0][dt], 0, 0, 0);
      o[1][dt] = __builtin_amdgcn_mfma_f32_16x16x32_bf16(pf1, vf, o[1][dt], 0, 0, 0);
    }
  }

  // row-sum reduction: 16-lane butterfly within quad groups, once
#pragma unroll
  for (int mi = 0; mi < 2; ++mi)
#pragma unroll
    for (int r = 0; r < 4; ++r) {
#pragma unroll
      for (int off = 1; off < 16; off <<= 1)
        lsum[mi][r] += __shfl_xor(lsum[mi][r], off, 64);
    }
  if (lane16 == 0) {
#pragma unroll
    for (int mi = 0; mi < 2; ++mi)
#pragma unroll
      for (int r = 0; r < 4; ++r)
        Lpart[((size_t)z * BN + b) * ND + q0 + (w * 2 + mi) * 16 + quad * 4 + r] =
            lsum[mi][r];
  }

  __syncthreads();
  // unnormalized O -> transposed bf16 staging ot[d][q_local]
#pragma unroll
  for (int mi = 0; mi < 2; ++mi)
#pragma unroll
    for (int dt = 0; dt < 16; ++dt)
#pragma unroll
      for (int r = 0; r < 4; ++r)
        sm.ot[dt * 16 + lane16][(w * 2 + mi) * 16 + quad * 4 + r] =
            f2bf(o[mi][dt][r]);
  __syncthreads();
  const size_t SZc = (size_t)BN * ND * CD;
  u16* Op = Opart + (size_t)z * SZc;
#pragma unroll
  for (int it = 0; it < 16; ++it) {
    int c = it * 256 + t;
    int dd = c >> 4, co = (c & 15) * 8;
    size_t g = ((size_t)b * CD + dd) * ND + q0 + co;
    *(uint4*)(Op + g) = *(const uint4*)&sm.ot[dd][co];
  }

  // ---- fused combine: last z-block for this (q-tile, b) ----
  __threadfence();        // release our O + Lpart stores (device scope)
  __syncthreads();        // all threads' fences retired before the ticket
  if (t == 0)
    lastFlag = (atomicAdd(&cnt[blockIdx.x * BN + b], 1) == NS - 1);
  __syncthreads();
  if (!lastFlag) return;
  __threadfence();        // acquire: other blocks' partials now visible

  if (t < 128) {
    float s = 0.f;
#pragma unroll
    for (int z2 = 0; z2 < NS; ++z2)
      s += Lpart[((size_t)z2 * BN + b) * ND + q0 + t];
    sm.ls[t] = 1.f / s;
  }
  __syncthreads();
#pragma unroll
  for (int it = 0; it < 16; ++it) {
    int idx = it * 256 + t;
    int dd = idx >> 4, qo = (idx & 15) * 8;
    size_t g = ((size_t)b * CD + dd) * ND + q0 + qo;
    float av[8] = {0.f, 0.f, 0.f, 0.f, 0.f, 0.f, 0.f, 0.f};
#pragma unroll
    for (int z2 = 0; z2 < NS; ++z2) {
      union { uint4 q4; u16 s[8]; } u;
      u.q4 = *(const uint4*)(Opart + (size_t)z2 * SZc + g);
#pragma unroll
      for (int j = 0; j < 8; ++j) av[j] += bf2f(u.s[j]);
    }
    float4 x0 = *(const float4*)(x + g);
    float4 x1 = *(const float4*)(x + g + 4);
    float4 r0, r1;
    r0.x = x0.x + av[0] * sm.ls[qo + 0];
    r0.y = x0.y + av[1] * sm.ls[qo + 1];
    r0.z = x0.z + av[2] * sm.ls[qo + 2];
    r0.w = x0.w + av[3] * sm.ls[qo + 3];
    r1.x = x1.x + av[4] * sm.ls[qo + 4];
    r1.y = x1.y + av[5] * sm.ls[qo + 5];
    r1.z = x1.z + av[6] * sm.ls[qo + 6];
    r1.w = x1.w + av[7] * sm.ls[qo + 7];
    *(float4*)(out + g) = r0;
    *(float4*)(out + g + 4) = r1;
  }
}

extern "C" void kernel_launch(void* const* d_in, const int* in_sizes, int n_in,
                              void* d_out, int out_size, void* d_ws, size_t ws_size,
                              hipStream_t stream) {
  const float* x  = (const float*)d_in[0];
  const float* y  = (const float*)d_in[1];
  const float* Wq = (const float*)d_in[2];
  const float* bq = (const float*)d_in[3];
  const float* Wk = (const float*)d_in[4];
  const float* bk = (const float*)d_in[5];
  const float* Wv = (const float*)d_in[6];
  const float* bv = (const float*)d_in[7];
  float* out = (float*)d_out;
  u16* ws = (u16*)d_ws;
  const size_t SZ = (size_t)BN * ND * CD;  // 4,194,304 elems per tensor
  u16* Qb = ws;
  u16* Kb = Qb + SZ;
  u16* Vb = Kb + SZ;
  u16* Ob = Vb + SZ;  // NS partials, contiguous
  // NS=4 needs: 7*SZ bf16 + 4*BN*ND fp32 (L) + counters
  const size_t need4 =
      7 * SZ * sizeof(u16) + (size_t)4 * BN * ND * sizeof(float) + 4096;
  const bool big = ws_size >= need4;  // constant across calls (graph-safe)

  k_projQK<<<dim3(256, 2), 256, 0, stream>>>(x, y, Wq, Wk, bq, bk, Qb, Kb);
  k_projV<<<dim3(64, 4), 256, 0, stream>>>(y, Wv, bv, Vb);
  if (big) {
    float* Lp = (float*)(Ob + 4 * SZ);
    int* cnt = (int*)(Lp + (size_t)4 * BN * ND);
    hipMemsetAsync(cnt, 0, (ND / 128) * BN * sizeof(int), stream);
    k_attn<4><<<dim3(ND / 128, BN, 4), 256, 0, stream>>>(
        Qb, Kb, Vb, Ob, Lp, cnt, x, out);
  } else {
    float* Lp = (float*)(Ob + 2 * SZ);
    int* cnt = (int*)(Lp + (size_t)2 * BN * ND);
    hipMemsetAsync(cnt, 0, (ND / 128) * BN * sizeof(int), stream);
    k_attn<2><<<dim3(ND / 128, BN, 2), 256, 0, stream>>>(
        Qb, Kb, Vb, Ob, Lp, cnt, x, out);
  }
}

// Round 12
// 199.096 us; speedup vs baseline: 1.3867x; 1.3867x over previous
//
#include <hip/hip_runtime.h>
#include <stdint.h>

#define BN 4
#define CD 256
#define ND 4096
#define NK 32            // key-tile size in attention

typedef unsigned short u16;
typedef short bfrag __attribute__((ext_vector_type(8)));  // 8 bf16 = 4 VGPR
typedef float ffrag __attribute__((ext_vector_type(4)));  // MFMA C/D frag

__device__ __forceinline__ float bf2f(u16 u) {
  union { unsigned int i; float f; } v;
  v.i = ((unsigned int)u) << 16;
  return v.f;
}
__device__ __forceinline__ u16 f2bf(float f) {
  union { float f; unsigned int i; } v;
  v.f = f;
  return (u16)((v.i + 0x7FFFu + ((v.i >> 16) & 1u)) >> 16);  // RNE
}
// async global->LDS DMA, 16B per lane; LDS dest = wave-uniform base + lane*16
__device__ __forceinline__ void gload_lds(const u16* g, u16* l) {
  __builtin_amdgcn_global_load_lds(
      (const __attribute__((address_space(1))) void*)g,
      (__attribute__((address_space(3))) void*)l, 16, 0, 0);
}

// ---------- Q/K projection, direct from fp32, one block = 64 rows x 256 d --
// grid (256, 2). Input tile transposed+cast to LDS ONCE with conflict-free
// lane assignment (lane u writes rows {u,16+u,32+u,48+u} of column c);
// weights chunk-staged to LDS with inline fp32->bf16 cast.
__global__ __launch_bounds__(256, 2) void k_projQK(
    const float* __restrict__ x, const float* __restrict__ y,
    const float* __restrict__ Wq, const float* __restrict__ Wk,
    const float* __restrict__ bq, const float* __restrict__ bk,
    u16* __restrict__ Qb, u16* __restrict__ Kb) {
  __shared__ alignas(16) u16 As[64][264];  // As[n][c], input^T cast
  __shared__ alignas(16) u16 Ws[64][264];  // weight chunk [d_local][c]
  int m0 = blockIdx.x * 64;
  int z = blockIdx.y;
  int b = m0 >> 12, nsp = m0 & 4095;
  const float* src = (z ? y : x) + (size_t)b * CD * ND;
  const float* Wf = z ? Wk : Wq;
  const float* bias = z ? bk : bq;
  u16* Cd = (z ? Kb : Qb) + (size_t)m0 * CD;
  int t = threadIdx.x, w = t >> 6, l = t & 63;
  int lane16 = l & 15, quad = l >> 4;

  // A-staging, conflict-free: lane u = t&15 writes rows j*16+u of col c
  {
    int u = t & 15, grp = t >> 4;
#pragma unroll
    for (int it = 0; it < 16; ++it) {
      int c = it * 16 + grp;
      const float* col = src + (size_t)c * ND + nsp;
#pragma unroll
      for (int j = 0; j < 4; ++j)
        As[j * 16 + u][c] = f2bf(col[j * 16 + u]);
    }
  }
  __syncthreads();

  // A-frags in registers (rows w*16+lane16)
  bfrag af[8];
#pragma unroll
  for (int kc = 0; kc < 8; ++kc)
    af[kc] = *(const bfrag*)&As[w * 16 + lane16][kc * 32 + quad * 8];

  ffrag acc[16];
#pragma unroll
  for (int i = 0; i < 16; ++i) acc[i] = ffrag{0.f, 0.f, 0.f, 0.f};

#pragma unroll
  for (int c4 = 0; c4 < 4; ++c4) {  // 4 chunks of 64 d
    if (c4) __syncthreads();        // prior MFMA done reading Ws
#pragma unroll
    for (int it = 0; it < 16; ++it) {
      int idx = it * 256 + t;
      int row = idx >> 6, col = (idx & 63) * 4;
      float4 v = *(const float4*)(Wf + (size_t)(c4 * 64 + row) * CD + col);
      ushort4 o;
      o.x = f2bf(v.x); o.y = f2bf(v.y); o.z = f2bf(v.z); o.w = f2bf(v.w);
      *(ushort4*)&Ws[row][col] = o;
    }
    __syncthreads();
#pragma unroll
    for (int kc = 0; kc < 8; ++kc)
#pragma unroll
      for (int tt = 0; tt < 4; ++tt) {
        bfrag bfr = *(const bfrag*)&Ws[tt * 16 + lane16][kc * 32 + quad * 8];
        acc[c4 * 4 + tt] =
            __builtin_amdgcn_mfma_f32_16x16x32_bf16(af[kc], bfr, acc[c4 * 4 + tt], 0, 0, 0);
      }
  }
  // epilogue: row = w*16+quad*4+r, col = nt*16+lane16
#pragma unroll
  for (int nt = 0; nt < 16; ++nt) {
    int col = nt * 16 + lane16;
    float bcol = bias[col];
#pragma unroll
    for (int r = 0; r < 4; ++r) {
      int rowL = w * 16 + quad * 4 + r;
      Cd[(size_t)rowL * CD + col] = f2bf(acc[nt][r] + bcol);
    }
  }
}

// ---------- V projection, direct from fp32, out Vt[b][d][n] ----------
// grid (64, 4). y^T tile staged ONCE (conflict-free); Wv chunk-staged.
__global__ __launch_bounds__(256, 2) void k_projV(
    const float* __restrict__ y, const float* __restrict__ Wv,
    const float* __restrict__ bv, u16* __restrict__ Vb) {
  __shared__ alignas(16) u16 Bs[64][264];  // Bs[n][c] = y^T cast
  __shared__ alignas(16) u16 Ws[64][264];  // Wv chunk [d_local][c]
  int n0s = blockIdx.x * 64;
  int b = blockIdx.y;
  const float* src = y + (size_t)b * CD * ND;
  u16* Cd = Vb + (size_t)b * CD * ND;
  int t = threadIdx.x, w = t >> 6, l = t & 63;
  int lane16 = l & 15, quad = l >> 4;

  // B-staging, conflict-free lane assignment
  {
    int u = t & 15, grp = t >> 4;
#pragma unroll
    for (int it = 0; it < 16; ++it) {
      int c = it * 16 + grp;
      const float* col = src + (size_t)c * ND + n0s;
#pragma unroll
      for (int j = 0; j < 4; ++j)
        Bs[j * 16 + u][c] = f2bf(col[j * 16 + u]);
    }
  }
  __syncthreads();

  // B-frags in registers (n rows w*16+lane16)
  bfrag bfr8[8];
#pragma unroll
  for (int kc = 0; kc < 8; ++kc)
    bfr8[kc] = *(const bfrag*)&Bs[w * 16 + lane16][kc * 32 + quad * 8];

  ffrag o[16];
#pragma unroll
  for (int i = 0; i < 16; ++i) o[i] = ffrag{0.f, 0.f, 0.f, 0.f};

#pragma unroll
  for (int c4 = 0; c4 < 4; ++c4) {  // 4 chunks of 64 d
    if (c4) __syncthreads();
#pragma unroll
    for (int it = 0; it < 16; ++it) {
      int idx = it * 256 + t;
      int row = idx >> 6, col = (idx & 63) * 4;
      float4 v = *(const float4*)(Wv + (size_t)(c4 * 64 + row) * CD + col);
      ushort4 ov;
      ov.x = f2bf(v.x); ov.y = f2bf(v.y); ov.z = f2bf(v.z); ov.w = f2bf(v.w);
      *(ushort4*)&Ws[row][col] = ov;
    }
    __syncthreads();
#pragma unroll
    for (int kc = 0; kc < 8; ++kc)
#pragma unroll
      for (int mt = 0; mt < 4; ++mt) {
        bfrag af = *(const bfrag*)&Ws[mt * 16 + lane16][kc * 32 + quad * 8];
        o[c4 * 4 + mt] =
            __builtin_amdgcn_mfma_f32_16x16x32_bf16(af, bfr8[kc], o[c4 * 4 + mt], 0, 0, 0);
      }
  }
  // epilogue: d = c4*64 + mt*16 + quad*4 + r
#pragma unroll
  for (int i = 0; i < 16; ++i) {
    int c4 = i >> 2, mt = i & 3;
#pragma unroll
    for (int r = 0; r < 4; ++r) {
      int d = c4 * 64 + mt * 16 + quad * 4 + r;
      Cd[(size_t)d * ND + n0s + w * 16 + lane16] = f2bf(o[i][r] + bv[d]);
    }
  }
}

// ---------- flash attention, split-K, async-DMA double-buffered ----------
// Q,K: [B*N][C]; Vt: [B][C][N]. 128 q-rows/block, 4 waves x 2 m-tiles.
// One __syncthreads per K-tile. XOR-swizzled unpadded LDS (global_load_lds).
union SmemU {
  struct {
    u16 Ks[2][NK][256];   // 32,768 B  chunk^=(row&7) swizzle
    u16 Vs[2][CD][NK];    // 32,768 B  chunk^=((d>>1)&3) swizzle
    u16 Ps[8][16][40];    // 10,240 B  wave-private P staging
  } a;                     // 75,776 B
  u16 ot[CD][136];         // 69,632 B  epilogue O^T staging
};

template <int NS>
__global__ __launch_bounds__(256, 2) void k_attn(
    const u16* __restrict__ Q, const u16* __restrict__ K,
    const u16* __restrict__ Vt, u16* __restrict__ O01,
    u16* __restrict__ O23, float* __restrict__ Lpart) {
  constexpr int NIT = ND / NS / NK;
  __shared__ alignas(16) SmemU sm;
  int b = blockIdx.y, q0 = blockIdx.x * 128, z = blockIdx.z;
  int t = threadIdx.x, w = t >> 6, l = t & 63;
  int lane16 = l & 15, quad = l >> 4;
  const float scale = 0.0625f;  // 256^-0.5

  // Q frags: A-layout rows q0 + (w*2+mi)*16 + lane16
  bfrag qf[2][8];
#pragma unroll
  for (int mi = 0; mi < 2; ++mi) {
    const u16* Qrow =
        Q + ((size_t)b * ND + q0 + (w * 2 + mi) * 16 + lane16) * CD;
#pragma unroll
    for (int kc = 0; kc < 8; ++kc)
      qf[mi][kc] = *(const bfrag*)(Qrow + kc * 32 + quad * 8);
  }

  ffrag o[2][16];
#pragma unroll
  for (int mi = 0; mi < 2; ++mi)
#pragma unroll
    for (int i = 0; i < 16; ++i) o[mi][i] = ffrag{0.f, 0.f, 0.f, 0.f};
  float lsum[2][4] = {{0.f, 0.f, 0.f, 0.f}, {0.f, 0.f, 0.f, 0.f}};

  const u16* Kb = K + ((size_t)b * ND + z * (ND / NS)) * CD;
  const u16* Vb = Vt + (size_t)b * CD * ND + z * (ND / NS);

  auto stage = [&](int kt2) {
    int dbuf = kt2 & 1;
    const u16* Kt = Kb + (size_t)kt2 * NK * CD;
    const u16* Vtt = Vb + kt2 * NK;
#pragma unroll
    for (int p = 0; p < 4; ++p) {
      int r = p * 8 + w * 2 + (l >> 5);
      int j = (l & 31) ^ (r & 7);
      gload_lds(Kt + (size_t)r * CD + j * 8, &sm.a.Ks[dbuf][p * 8 + w * 2][0]);
    }
#pragma unroll
    for (int p = 0; p < 4; ++p) {
      int dd = p * 64 + w * 16 + (l >> 2);
      int j = (l & 3) ^ ((dd >> 1) & 3);
      gload_lds(Vtt + (size_t)dd * ND + j * 8, &sm.a.Vs[dbuf][p * 64 + w * 16][0]);
    }
  };

  stage(0);
  for (int kt = 0; kt < NIT; ++kt) {
    int dbuf = kt & 1;
    __syncthreads();  // drains DMA for buf dbuf; recycling of dbuf^1 is safe
    if (kt + 1 < NIT) stage(kt + 1);  // async into other buffer, no wait

    // S = Q K^T  (2 m-tiles x 2 key-tiles)
    ffrag s2[2][2];
#pragma unroll
    for (int mi = 0; mi < 2; ++mi)
#pragma unroll
      for (int tt = 0; tt < 2; ++tt) s2[mi][tt] = ffrag{0.f, 0.f, 0.f, 0.f};
#pragma unroll
    for (int kc = 0; kc < 8; ++kc) {
      bfrag kf0, kf1;
      {
        int r = lane16;
        int cp = (kc * 4 + quad) ^ (r & 7);
        kf0 = *(const bfrag*)&sm.a.Ks[dbuf][r][cp * 8];
        int r1 = 16 + lane16;
        int cp1 = (kc * 4 + quad) ^ (r1 & 7);
        kf1 = *(const bfrag*)&sm.a.Ks[dbuf][r1][cp1 * 8];
      }
#pragma unroll
      for (int mi = 0; mi < 2; ++mi) {
        s2[mi][0] = __builtin_amdgcn_mfma_f32_16x16x32_bf16(qf[mi][kc], kf0,
                                                            s2[mi][0], 0, 0, 0);
        s2[mi][1] = __builtin_amdgcn_mfma_f32_16x16x32_bf16(qf[mi][kc], kf1,
                                                            s2[mi][1], 0, 0, 0);
      }
    }

    // fixed-max softmax: p = exp(s*scale); lane-partial sums; P -> LDS
#pragma unroll
    for (int mi = 0; mi < 2; ++mi)
#pragma unroll
      for (int tt = 0; tt < 2; ++tt)
#pragma unroll
        for (int r = 0; r < 4; ++r) {
          float p = __expf(s2[mi][tt][r] * scale);
          lsum[mi][r] += p;
          sm.a.Ps[w * 2 + mi][quad * 4 + r][tt * 16 + lane16] = f2bf(p);
        }
    // wave-private Ps: in-wave LDS ordering suffices, no barrier
    bfrag pf0 = *(const bfrag*)&sm.a.Ps[w * 2 + 0][lane16][quad * 8];
    bfrag pf1 = *(const bfrag*)&sm.a.Ps[w * 2 + 1][lane16][quad * 8];

    // O += P V  (16 d-tiles, V-frag shared across both m-tiles)
#pragma unroll
    for (int dt = 0; dt < 16; ++dt) {
      int dd = dt * 16 + lane16;
      int cp = quad ^ ((dd >> 1) & 3);
      bfrag vf = *(const bfrag*)&sm.a.Vs[dbuf][dd][cp * 8];
      o[0][dt] = __builtin_amdgcn_mfma_f32_16x16x32_bf16(pf0, vf, o[0][dt], 0, 0, 0);
      o[1][dt] = __builtin_amdgcn_mfma_f32_16x16x32_bf16(pf1, vf, o[1][dt], 0, 0, 0);
    }
  }

  // row-sum reduction: 16-lane butterfly within quad groups, once
#pragma unroll
  for (int mi = 0; mi < 2; ++mi)
#pragma unroll
    for (int r = 0; r < 4; ++r) {
#pragma unroll
      for (int off = 1; off < 16; off <<= 1)
        lsum[mi][r] += __shfl_xor(lsum[mi][r], off, 64);
    }
  if (lane16 == 0) {
#pragma unroll
    for (int mi = 0; mi < 2; ++mi)
#pragma unroll
      for (int r = 0; r < 4; ++r)
        Lpart[((size_t)z * BN + b) * ND + q0 + (w * 2 + mi) * 16 + quad * 4 + r] =
            lsum[mi][r];
  }

  __syncthreads();
  // unnormalized O -> transposed bf16 staging ot[d][q_local]
#pragma unroll
  for (int mi = 0; mi < 2; ++mi)
#pragma unroll
    for (int dt = 0; dt < 16; ++dt)
#pragma unroll
      for (int r = 0; r < 4; ++r)
        sm.ot[dt * 16 + lane16][(w * 2 + mi) * 16 + quad * 4 + r] =
            f2bf(o[mi][dt][r]);
  __syncthreads();
  const size_t SZc = (size_t)BN * ND * CD;
  u16* Op = ((z < 2) ? O01 : O23) + (size_t)(z & 1) * SZc;
#pragma unroll
  for (int it = 0; it < 16; ++it) {
    int c = it * 256 + t;
    int dd = c >> 4, co = (c & 15) * 8;
    size_t g = ((size_t)b * CD + dd) * ND + q0 + co;
    *(uint4*)(Op + g) = *(const uint4*)&sm.ot[dd][co];
  }
}

// ---------- combine partials + residual ----------
template <int NS>
__global__ __launch_bounds__(256) void k_combine(
    const u16* __restrict__ O01, const u16* __restrict__ O23,
    const float* __restrict__ L, const float* __restrict__ x,
    float* __restrict__ out) {
  const size_t SZc = (size_t)BN * ND * CD;
  size_t e = ((size_t)blockIdx.x * 256 + threadIdx.x) * 8;
  int n = (int)(e & (ND - 1));
  int b = (int)(e >> 20);  // C*N = 2^20
  float ls[8] = {0, 0, 0, 0, 0, 0, 0, 0};
  float acc[8] = {0, 0, 0, 0, 0, 0, 0, 0};
#pragma unroll
  for (int z = 0; z < NS; ++z) {
    const float* Lr = L + ((size_t)z * BN + b) * ND + n;
    float4 l0 = *(const float4*)(Lr);
    float4 l1 = *(const float4*)(Lr + 4);
    ls[0] += l0.x; ls[1] += l0.y; ls[2] += l0.z; ls[3] += l0.w;
    ls[4] += l1.x; ls[5] += l1.y; ls[6] += l1.z; ls[7] += l1.w;
    const u16* Oz = ((z < 2) ? O01 : O23) + (size_t)(z & 1) * SZc + e;
    union { uint4 q; u16 s[8]; } u;
    u.q = *(const uint4*)Oz;
#pragma unroll
    for (int j = 0; j < 8; ++j) acc[j] += bf2f(u.s[j]);
  }
  float4 x0 = *(const float4*)(x + e);
  float4 x1 = *(const float4*)(x + e + 4);
  float4 r0, r1;
  r0.x = x0.x + acc[0] / ls[0];
  r0.y = x0.y + acc[1] / ls[1];
  r0.z = x0.z + acc[2] / ls[2];
  r0.w = x0.w + acc[3] / ls[3];
  r1.x = x1.x + acc[4] / ls[4];
  r1.y = x1.y + acc[5] / ls[5];
  r1.z = x1.z + acc[6] / ls[6];
  r1.w = x1.w + acc[7] / ls[7];
  *(float4*)(out + e) = r0;
  *(float4*)(out + e + 4) = r1;
}

extern "C" void kernel_launch(void* const* d_in, const int* in_sizes, int n_in,
                              void* d_out, int out_size, void* d_ws, size_t ws_size,
                              hipStream_t stream) {
  const float* x  = (const float*)d_in[0];
  const float* y  = (const float*)d_in[1];
  const float* Wq = (const float*)d_in[2];
  const float* bq = (const float*)d_in[3];
  const float* Wk = (const float*)d_in[4];
  const float* bk = (const float*)d_in[5];
  const float* Wv = (const float*)d_in[6];
  const float* bv = (const float*)d_in[7];
  float* out = (float*)d_out;
  u16* ws = (u16*)d_ws;
  const size_t SZ = (size_t)BN * ND * CD;  // 4,194,304 elems per tensor
  u16* Qb = ws;
  u16* Kb = Qb + SZ;
  u16* Vb = Kb + SZ;
  u16* Ob = Vb + SZ;  // NS partials, contiguous
  // NS=4: 7*SZ bf16 + 4*BN*ND fp32 = 58.7 MB + 256 KB
  const size_t need4 = 7 * SZ * sizeof(u16) + (size_t)4 * BN * ND * sizeof(float);
  const bool big = ws_size >= need4;  // constant across calls (graph-safe)
  const int cgrid = (int)(SZ / (256 * 8));  // 2048 blocks (out = SZ floats)

  k_projQK<<<dim3(256, 2), 256, 0, stream>>>(x, y, Wq, Wk, bq, bk, Qb, Kb);
  k_projV<<<dim3(64, 4), 256, 0, stream>>>(y, Wv, bv, Vb);
  if (big) {
    float* Lp = (float*)(Ob + 4 * SZ);
    k_attn<4><<<dim3(ND / 128, BN, 4), 256, 0, stream>>>(Qb, Kb, Vb, Ob,
                                                         Ob + 2 * SZ, Lp);
    k_combine<4><<<dim3(cgrid), 256, 0, stream>>>(Ob, Ob + 2 * SZ, Lp, x, out);
  } else {
    float* Lp = (float*)(Ob + 2 * SZ);
    k_attn<2><<<dim3(ND / 128, BN, 2), 256, 0, stream>>>(Qb, Kb, Vb, Ob, Ob, Lp);
    k_combine<2><<<dim3(cgrid), 256, 0, stream>>>(Ob, Ob, Lp, x, out);
  }
}

// Round 13
// 194.541 us; speedup vs baseline: 1.4192x; 1.0234x over previous
//
#include <hip/hip_runtime.h>
#include <stdint.h>

#define BN 4
#define CD 256
#define ND 4096
#define NK 32            // key-tile size in attention

typedef unsigned short u16;
typedef short bfrag __attribute__((ext_vector_type(8)));  // 8 bf16 = 4 VGPR
typedef float ffrag __attribute__((ext_vector_type(4)));  // MFMA C/D frag

__device__ __forceinline__ float bf2f(u16 u) {
  union { unsigned int i; float f; } v;
  v.i = ((unsigned int)u) << 16;
  return v.f;
}
__device__ __forceinline__ u16 f2bf(float f) {
  union { float f; unsigned int i; } v;
  v.f = f;
  return (u16)((v.i + 0x7FFFu + ((v.i >> 16) & 1u)) >> 16);  // RNE
}
// async global->LDS DMA, 16B per lane; LDS dest = wave-uniform base + lane*16
__device__ __forceinline__ void gload_lds(const u16* g, u16* l) {
  __builtin_amdgcn_global_load_lds(
      (const __attribute__((address_space(1))) void*)g,
      (__attribute__((address_space(3))) void*)l, 16, 0, 0);
}

// ---------- merged projections: grid (64, 4, 3) ----------
// z in {0,1}: Q/K path, m0 = (y*64+x)*64 (r12 k_projQK body verbatim).
// z == 2   : V path, n0s = x*64, b = y   (r12 k_projV body verbatim).
__global__ __launch_bounds__(256, 2) void k_proj3(
    const float* __restrict__ x, const float* __restrict__ y,
    const float* __restrict__ Wq, const float* __restrict__ Wk,
    const float* __restrict__ Wv, const float* __restrict__ bq,
    const float* __restrict__ bk, const float* __restrict__ bv,
    u16* __restrict__ Qb, u16* __restrict__ Kb, u16* __restrict__ Vb) {
  __shared__ alignas(16) u16 S1[64][264];  // input^T cast (As / Bs)
  __shared__ alignas(16) u16 Ws[64][264];  // weight chunk [d_local][c]
  int t = threadIdx.x, w = t >> 6, l = t & 63;
  int lane16 = l & 15, quad = l >> 4;
  int zz = blockIdx.z;

  if (zz < 2) {
    // ------- Q/K path -------
    int m0 = (blockIdx.y * 64 + blockIdx.x) * 64;  // [0, 16384)
    int z = zz;
    int b = m0 >> 12, nsp = m0 & 4095;
    const float* src = (z ? y : x) + (size_t)b * CD * ND;
    const float* Wf = z ? Wk : Wq;
    const float* bias = z ? bk : bq;
    u16* Cd = (z ? Kb : Qb) + (size_t)m0 * CD;

    // A-staging, conflict-free: lane u = t&15 writes rows j*16+u of col c
    {
      int u = t & 15, grp = t >> 4;
#pragma unroll
      for (int it = 0; it < 16; ++it) {
        int c = it * 16 + grp;
        const float* col = src + (size_t)c * ND + nsp;
#pragma unroll
        for (int j = 0; j < 4; ++j)
          S1[j * 16 + u][c] = f2bf(col[j * 16 + u]);
      }
    }
    __syncthreads();

    bfrag af[8];
#pragma unroll
    for (int kc = 0; kc < 8; ++kc)
      af[kc] = *(const bfrag*)&S1[w * 16 + lane16][kc * 32 + quad * 8];

    ffrag acc[16];
#pragma unroll
    for (int i = 0; i < 16; ++i) acc[i] = ffrag{0.f, 0.f, 0.f, 0.f};

#pragma unroll
    for (int c4 = 0; c4 < 4; ++c4) {  // 4 chunks of 64 d
      if (c4) __syncthreads();
#pragma unroll
      for (int it = 0; it < 16; ++it) {
        int idx = it * 256 + t;
        int row = idx >> 6, col = (idx & 63) * 4;
        float4 v = *(const float4*)(Wf + (size_t)(c4 * 64 + row) * CD + col);
        ushort4 o;
        o.x = f2bf(v.x); o.y = f2bf(v.y); o.z = f2bf(v.z); o.w = f2bf(v.w);
        *(ushort4*)&Ws[row][col] = o;
      }
      __syncthreads();
#pragma unroll
      for (int kc = 0; kc < 8; ++kc)
#pragma unroll
        for (int tt = 0; tt < 4; ++tt) {
          bfrag bfr = *(const bfrag*)&Ws[tt * 16 + lane16][kc * 32 + quad * 8];
          acc[c4 * 4 + tt] = __builtin_amdgcn_mfma_f32_16x16x32_bf16(
              af[kc], bfr, acc[c4 * 4 + tt], 0, 0, 0);
        }
    }
#pragma unroll
    for (int nt = 0; nt < 16; ++nt) {
      int col = nt * 16 + lane16;
      float bcol = bias[col];
#pragma unroll
      for (int r = 0; r < 4; ++r) {
        int rowL = w * 16 + quad * 4 + r;
        Cd[(size_t)rowL * CD + col] = f2bf(acc[nt][r] + bcol);
      }
    }
  } else {
    // ------- V path -------
    int n0s = blockIdx.x * 64;
    int b = blockIdx.y;
    const float* src = y + (size_t)b * CD * ND;
    u16* Cd = Vb + (size_t)b * CD * ND;

    // B-staging, conflict-free lane assignment
    {
      int u = t & 15, grp = t >> 4;
#pragma unroll
      for (int it = 0; it < 16; ++it) {
        int c = it * 16 + grp;
        const float* col = src + (size_t)c * ND + n0s;
#pragma unroll
        for (int j = 0; j < 4; ++j)
          S1[j * 16 + u][c] = f2bf(col[j * 16 + u]);
      }
    }
    __syncthreads();

    bfrag bfr8[8];
#pragma unroll
    for (int kc = 0; kc < 8; ++kc)
      bfr8[kc] = *(const bfrag*)&S1[w * 16 + lane16][kc * 32 + quad * 8];

    ffrag o[16];
#pragma unroll
    for (int i = 0; i < 16; ++i) o[i] = ffrag{0.f, 0.f, 0.f, 0.f};

#pragma unroll
    for (int c4 = 0; c4 < 4; ++c4) {  // 4 chunks of 64 d
      if (c4) __syncthreads();
#pragma unroll
      for (int it = 0; it < 16; ++it) {
        int idx = it * 256 + t;
        int row = idx >> 6, col = (idx & 63) * 4;
        float4 v = *(const float4*)(Wv + (size_t)(c4 * 64 + row) * CD + col);
        ushort4 ov;
        ov.x = f2bf(v.x); ov.y = f2bf(v.y); ov.z = f2bf(v.z); ov.w = f2bf(v.w);
        *(ushort4*)&Ws[row][col] = ov;
      }
      __syncthreads();
#pragma unroll
      for (int kc = 0; kc < 8; ++kc)
#pragma unroll
        for (int mt = 0; mt < 4; ++mt) {
          bfrag af = *(const bfrag*)&Ws[mt * 16 + lane16][kc * 32 + quad * 8];
          o[c4 * 4 + mt] = __builtin_amdgcn_mfma_f32_16x16x32_bf16(
              af, bfr8[kc], o[c4 * 4 + mt], 0, 0, 0);
        }
    }
#pragma unroll
    for (int i = 0; i < 16; ++i) {
      int c4 = i >> 2, mt = i & 3;
#pragma unroll
      for (int r = 0; r < 4; ++r) {
        int d = c4 * 64 + mt * 16 + quad * 4 + r;
        Cd[(size_t)d * ND + n0s + w * 16 + lane16] = f2bf(o[i][r] + bv[d]);
      }
    }
  }
}

// ---------- flash attention, split-K, async-DMA double-buffered ----------
// Q,K: [B*N][C]; Vt: [B][C][N]. 128 q-rows/block, 4 waves x 2 m-tiles.
// One __syncthreads per K-tile. XOR-swizzled unpadded LDS (global_load_lds).
union SmemU {
  struct {
    u16 Ks[2][NK][256];   // 32,768 B  chunk^=(row&7) swizzle
    u16 Vs[2][CD][NK];    // 32,768 B  chunk^=((d>>1)&3) swizzle
    u16 Ps[8][16][40];    // 10,240 B  wave-private P staging
  } a;                     // 75,776 B
  u16 ot[CD][136];         // 69,632 B  epilogue O^T staging
};

template <int NS>
__global__ __launch_bounds__(256, 2) void k_attn(
    const u16* __restrict__ Q, const u16* __restrict__ K,
    const u16* __restrict__ Vt, u16* __restrict__ O01,
    u16* __restrict__ O23, float* __restrict__ Lpart) {
  constexpr int NIT = ND / NS / NK;
  __shared__ alignas(16) SmemU sm;
  int b = blockIdx.y, q0 = blockIdx.x * 128, z = blockIdx.z;
  int t = threadIdx.x, w = t >> 6, l = t & 63;
  int lane16 = l & 15, quad = l >> 4;
  const float scale = 0.0625f;  // 256^-0.5

  // Q frags: A-layout rows q0 + (w*2+mi)*16 + lane16
  bfrag qf[2][8];
#pragma unroll
  for (int mi = 0; mi < 2; ++mi) {
    const u16* Qrow =
        Q + ((size_t)b * ND + q0 + (w * 2 + mi) * 16 + lane16) * CD;
#pragma unroll
    for (int kc = 0; kc < 8; ++kc)
      qf[mi][kc] = *(const bfrag*)(Qrow + kc * 32 + quad * 8);
  }

  ffrag o[2][16];
#pragma unroll
  for (int mi = 0; mi < 2; ++mi)
#pragma unroll
    for (int i = 0; i < 16; ++i) o[mi][i] = ffrag{0.f, 0.f, 0.f, 0.f};
  float lsum[2][4] = {{0.f, 0.f, 0.f, 0.f}, {0.f, 0.f, 0.f, 0.f}};

  const u16* Kb = K + ((size_t)b * ND + z * (ND / NS)) * CD;
  const u16* Vb = Vt + (size_t)b * CD * ND + z * (ND / NS);

  auto stage = [&](int kt2) {
    int dbuf = kt2 & 1;
    const u16* Kt = Kb + (size_t)kt2 * NK * CD;
    const u16* Vtt = Vb + kt2 * NK;
#pragma unroll
    for (int p = 0; p < 4; ++p) {
      int r = p * 8 + w * 2 + (l >> 5);
      int j = (l & 31) ^ (r & 7);
      gload_lds(Kt + (size_t)r * CD + j * 8, &sm.a.Ks[dbuf][p * 8 + w * 2][0]);
    }
#pragma unroll
    for (int p = 0; p < 4; ++p) {
      int dd = p * 64 + w * 16 + (l >> 2);
      int j = (l & 3) ^ ((dd >> 1) & 3);
      gload_lds(Vtt + (size_t)dd * ND + j * 8, &sm.a.Vs[dbuf][p * 64 + w * 16][0]);
    }
  };

  stage(0);
  for (int kt = 0; kt < NIT; ++kt) {
    int dbuf = kt & 1;
    __syncthreads();  // drains DMA for buf dbuf; recycling of dbuf^1 is safe
    if (kt + 1 < NIT) stage(kt + 1);  // async into other buffer, no wait

    // S = Q K^T  (2 m-tiles x 2 key-tiles)
    ffrag s2[2][2];
#pragma unroll
    for (int mi = 0; mi < 2; ++mi)
#pragma unroll
      for (int tt = 0; tt < 2; ++tt) s2[mi][tt] = ffrag{0.f, 0.f, 0.f, 0.f};
#pragma unroll
    for (int kc = 0; kc < 8; ++kc) {
      bfrag kf0, kf1;
      {
        int r = lane16;
        int cp = (kc * 4 + quad) ^ (r & 7);
        kf0 = *(const bfrag*)&sm.a.Ks[dbuf][r][cp * 8];
        int r1 = 16 + lane16;
        int cp1 = (kc * 4 + quad) ^ (r1 & 7);
        kf1 = *(const bfrag*)&sm.a.Ks[dbuf][r1][cp1 * 8];
      }
#pragma unroll
      for (int mi = 0; mi < 2; ++mi) {
        s2[mi][0] = __builtin_amdgcn_mfma_f32_16x16x32_bf16(qf[mi][kc], kf0,
                                                            s2[mi][0], 0, 0, 0);
        s2[mi][1] = __builtin_amdgcn_mfma_f32_16x16x32_bf16(qf[mi][kc], kf1,
                                                            s2[mi][1], 0, 0, 0);
      }
    }

    // fixed-max softmax: p = exp(s*scale); lane-partial sums; P -> LDS
#pragma unroll
    for (int mi = 0; mi < 2; ++mi)
#pragma unroll
      for (int tt = 0; tt < 2; ++tt)
#pragma unroll
        for (int r = 0; r < 4; ++r) {
          float p = __expf(s2[mi][tt][r] * scale);
          lsum[mi][r] += p;
          sm.a.Ps[w * 2 + mi][quad * 4 + r][tt * 16 + lane16] = f2bf(p);
        }
    // wave-private Ps: in-wave LDS ordering suffices, no barrier
    bfrag pf0 = *(const bfrag*)&sm.a.Ps[w * 2 + 0][lane16][quad * 8];
    bfrag pf1 = *(const bfrag*)&sm.a.Ps[w * 2 + 1][lane16][quad * 8];

    // O += P V  (16 d-tiles, V-frag shared across both m-tiles)
#pragma unroll
    for (int dt = 0; dt < 16; ++dt) {
      int dd = dt * 16 + lane16;
      int cp = quad ^ ((dd >> 1) & 3);
      bfrag vf = *(const bfrag*)&sm.a.Vs[dbuf][dd][cp * 8];
      o[0][dt] = __builtin_amdgcn_mfma_f32_16x16x32_bf16(pf0, vf, o[0][dt], 0, 0, 0);
      o[1][dt] = __builtin_amdgcn_mfma_f32_16x16x32_bf16(pf1, vf, o[1][dt], 0, 0, 0);
    }
  }

  // row-sum reduction: 16-lane butterfly within quad groups, once
#pragma unroll
  for (int mi = 0; mi < 2; ++mi)
#pragma unroll
    for (int r = 0; r < 4; ++r) {
#pragma unroll
      for (int off = 1; off < 16; off <<= 1)
        lsum[mi][r] += __shfl_xor(lsum[mi][r], off, 64);
    }
  if (lane16 == 0) {
#pragma unroll
    for (int mi = 0; mi < 2; ++mi)
#pragma unroll
      for (int r = 0; r < 4; ++r)
        Lpart[((size_t)z * BN + b) * ND + q0 + (w * 2 + mi) * 16 + quad * 4 + r] =
            lsum[mi][r];
  }

  __syncthreads();
  // unnormalized O -> transposed bf16 staging ot[d][q_local]
#pragma unroll
  for (int mi = 0; mi < 2; ++mi)
#pragma unroll
    for (int dt = 0; dt < 16; ++dt)
#pragma unroll
      for (int r = 0; r < 4; ++r)
        sm.ot[dt * 16 + lane16][(w * 2 + mi) * 16 + quad * 4 + r] =
            f2bf(o[mi][dt][r]);
  __syncthreads();
  const size_t SZc = (size_t)BN * ND * CD;
  u16* Op = ((z < 2) ? O01 : O23) + (size_t)(z & 1) * SZc;
#pragma unroll
  for (int it = 0; it < 16; ++it) {
    int c = it * 256 + t;
    int dd = c >> 4, co = (c & 15) * 8;
    size_t g = ((size_t)b * CD + dd) * ND + q0 + co;
    *(uint4*)(Op + g) = *(const uint4*)&sm.ot[dd][co];
  }
}

// ---------- combine partials + residual ----------
template <int NS>
__global__ __launch_bounds__(256) void k_combine(
    const u16* __restrict__ O01, const u16* __restrict__ O23,
    const float* __restrict__ L, const float* __restrict__ x,
    float* __restrict__ out) {
  const size_t SZc = (size_t)BN * ND * CD;
  size_t e = ((size_t)blockIdx.x * 256 + threadIdx.x) * 8;
  int n = (int)(e & (ND - 1));
  int b = (int)(e >> 20);  // C*N = 2^20
  float ls[8] = {0, 0, 0, 0, 0, 0, 0, 0};
  float acc[8] = {0, 0, 0, 0, 0, 0, 0, 0};
#pragma unroll
  for (int z = 0; z < NS; ++z) {
    const float* Lr = L + ((size_t)z * BN + b) * ND + n;
    float4 l0 = *(const float4*)(Lr);
    float4 l1 = *(const float4*)(Lr + 4);
    ls[0] += l0.x; ls[1] += l0.y; ls[2] += l0.z; ls[3] += l0.w;
    ls[4] += l1.x; ls[5] += l1.y; ls[6] += l1.z; ls[7] += l1.w;
    const u16* Oz = ((z < 2) ? O01 : O23) + (size_t)(z & 1) * SZc + e;
    union { uint4 q; u16 s[8]; } u;
    u.q = *(const uint4*)Oz;
#pragma unroll
    for (int j = 0; j < 8; ++j) acc[j] += bf2f(u.s[j]);
  }
  float4 x0 = *(const float4*)(x + e);
  float4 x1 = *(const float4*)(x + e + 4);
  float4 r0, r1;
  r0.x = x0.x + acc[0] / ls[0];
  r0.y = x0.y + acc[1] / ls[1];
  r0.z = x0.z + acc[2] / ls[2];
  r0.w = x0.w + acc[3] / ls[3];
  r1.x = x1.x + acc[4] / ls[4];
  r1.y = x1.y + acc[5] / ls[5];
  r1.z = x1.z + acc[6] / ls[6];
  r1.w = x1.w + acc[7] / ls[7];
  *(float4*)(out + e) = r0;
  *(float4*)(out + e + 4) = r1;
}

extern "C" void kernel_launch(void* const* d_in, const int* in_sizes, int n_in,
                              void* d_out, int out_size, void* d_ws, size_t ws_size,
                              hipStream_t stream) {
  const float* x  = (const float*)d_in[0];
  const float* y  = (const float*)d_in[1];
  const float* Wq = (const float*)d_in[2];
  const float* bq = (const float*)d_in[3];
  const float* Wk = (const float*)d_in[4];
  const float* bk = (const float*)d_in[5];
  const float* Wv = (const float*)d_in[6];
  const float* bv = (const float*)d_in[7];
  float* out = (float*)d_out;
  u16* ws = (u16*)d_ws;
  const size_t SZ = (size_t)BN * ND * CD;  // 4,194,304 elems per tensor
  u16* Qb = ws;
  u16* Kb = Qb + SZ;
  u16* Vb = Kb + SZ;
  u16* Ob = Vb + SZ;  // NS partials, contiguous
  // NS=4: 7*SZ bf16 + 4*BN*ND fp32 = 58.7 MB + 256 KB
  const size_t need4 = 7 * SZ * sizeof(u16) + (size_t)4 * BN * ND * sizeof(float);
  const bool big = ws_size >= need4;  // constant across calls (graph-safe)
  const int cgrid = (int)(SZ / (256 * 8));  // 2048 blocks (out = SZ floats)

  k_proj3<<<dim3(64, 4, 3), 256, 0, stream>>>(x, y, Wq, Wk, Wv, bq, bk, bv,
                                              Qb, Kb, Vb);
  if (big) {
    float* Lp = (float*)(Ob + 4 * SZ);
    k_attn<4><<<dim3(ND / 128, BN, 4), 256, 0, stream>>>(Qb, Kb, Vb, Ob,
                                                         Ob + 2 * SZ, Lp);
    k_combine<4><<<dim3(cgrid), 256, 0, stream>>>(Ob, Ob + 2 * SZ, Lp, x, out);
  } else {
    float* Lp = (float*)(Ob + 2 * SZ);
    k_attn<2><<<dim3(ND / 128, BN, 2), 256, 0, stream>>>(Qb, Kb, Vb, Ob, Ob, Lp);
    k_combine<2><<<dim3(cgrid), 256, 0, stream>>>(Ob, Ob, Lp, x, out);
  }
}

// Round 14
// 193.259 us; speedup vs baseline: 1.4286x; 1.0066x over previous
//
#include <hip/hip_runtime.h>
#include <stdint.h>

#define BN 4
#define CD 256
#define ND 4096
#define NK 32            // key-tile size in attention
#define WPK_M 65536      // u16 per packed weight matrix (8 kc * 16 nt * 512)

typedef unsigned short u16;
typedef short bfrag __attribute__((ext_vector_type(8)));  // 8 bf16 = 4 VGPR
typedef float ffrag __attribute__((ext_vector_type(4)));  // MFMA C/D frag

__device__ __forceinline__ float bf2f(u16 u) {
  union { unsigned int i; float f; } v;
  v.i = ((unsigned int)u) << 16;
  return v.f;
}
__device__ __forceinline__ u16 f2bf(float f) {
  union { float f; unsigned int i; } v;
  v.f = f;
  return (u16)((v.i + 0x7FFFu + ((v.i >> 16) & 1u)) >> 16);  // RNE
}
// async global->LDS DMA, 16B per lane; LDS dest = wave-uniform base + lane*16
__device__ __forceinline__ void gload_lds(const u16* g, u16* l) {
  __builtin_amdgcn_global_load_lds(
      (const __attribute__((address_space(1))) void*)g,
      (__attribute__((address_space(3))) void*)l, 16, 0, 0);
}

// ---------- pack weights into MFMA fragment order ----------
// frag-block (m, kc, nt): 1 KB; lane l holds W_m[nt*16+(l&15)][kc*32+(l>>4)*8+j]
// at offset l*16 B. Serves B-operand (QK) and A-operand (V) identically.
__global__ __launch_bounds__(256) void k_packW(
    const float* __restrict__ Wq, const float* __restrict__ Wk,
    const float* __restrict__ Wv, u16* __restrict__ Wpk) {
  int idx = blockIdx.x * 256 + threadIdx.x;  // 0..24575
  int lane = idx & 63;
  int fb = idx >> 6;                         // 0..383
  int nt = fb & 15, kc = (fb >> 4) & 7, m = fb >> 7;
  const float* W = (m == 0) ? Wq : ((m == 1) ? Wk : Wv);
  const float* s = W + (size_t)(nt * 16 + (lane & 15)) * CD + kc * 32 + (lane >> 4) * 8;
  u16* d = Wpk + (size_t)m * WPK_M + ((size_t)(kc * 16 + nt)) * 512 + lane * 8;
  float4 v0 = *(const float4*)(s);
  float4 v1 = *(const float4*)(s + 4);
  ushort4 o0, o1;
  o0.x = f2bf(v0.x); o0.y = f2bf(v0.y); o0.z = f2bf(v0.z); o0.w = f2bf(v0.w);
  o1.x = f2bf(v1.x); o1.y = f2bf(v1.y); o1.z = f2bf(v1.z); o1.w = f2bf(v1.w);
  *(ushort4*)(d) = o0;
  *(ushort4*)(d + 4) = o1;
}

// ---------- merged projections: grid (64, 4, 3), packed-frag weights ------
// z in {0,1}: Q/K path, m0 = (y*64+x)*64. z == 2: V path, n0s = x*64, b = y.
// Input tile transposed+cast to LDS once (1 barrier); weight frags are
// single coalesced 16B loads from Wpk (L2-hot), no W LDS, no casts.
__global__ __launch_bounds__(256, 4) void k_proj3(
    const float* __restrict__ x, const float* __restrict__ y,
    const u16* __restrict__ Wpk, const float* __restrict__ bq,
    const float* __restrict__ bk, const float* __restrict__ bv,
    u16* __restrict__ Qb, u16* __restrict__ Kb, u16* __restrict__ Vb) {
  __shared__ alignas(16) u16 S1[64][264];  // input^T cast
  int t = threadIdx.x, w = t >> 6, l = t & 63;
  int lane16 = l & 15, quad = l >> 4;
  int zz = blockIdx.z;

  if (zz < 2) {
    // ------- Q/K path -------
    int m0 = (blockIdx.y * 64 + blockIdx.x) * 64;  // [0, 16384)
    int b = m0 >> 12, nsp = m0 & 4095;
    const float* src = (zz ? y : x) + (size_t)b * CD * ND;
    const float* bias = zz ? bk : bq;
    u16* Cd = (zz ? Kb : Qb) + (size_t)m0 * CD;
    const u16* Wz = Wpk + (size_t)zz * WPK_M;

    // input staging, conflict-free: lane u = t&15 writes rows j*16+u of col c
    {
      int u = t & 15, grp = t >> 4;
#pragma unroll
      for (int it = 0; it < 16; ++it) {
        int c = it * 16 + grp;
        const float* col = src + (size_t)c * ND + nsp;
#pragma unroll
        for (int j = 0; j < 4; ++j)
          S1[j * 16 + u][c] = f2bf(col[j * 16 + u]);
      }
    }
    __syncthreads();

    bfrag af[8];
#pragma unroll
    for (int kc = 0; kc < 8; ++kc)
      af[kc] = *(const bfrag*)&S1[w * 16 + lane16][kc * 32 + quad * 8];

    ffrag acc[16];
#pragma unroll
    for (int i = 0; i < 16; ++i) acc[i] = ffrag{0.f, 0.f, 0.f, 0.f};

#pragma unroll
    for (int kc = 0; kc < 8; ++kc) {
      const u16* base = Wz + ((size_t)kc * 16) * 512 + l * 8;
#pragma unroll
      for (int nt = 0; nt < 16; ++nt) {
        bfrag bfr = *(const bfrag*)(base + nt * 512);
        acc[nt] = __builtin_amdgcn_mfma_f32_16x16x32_bf16(af[kc], bfr, acc[nt], 0, 0, 0);
      }
    }
#pragma unroll
    for (int nt = 0; nt < 16; ++nt) {
      int col = nt * 16 + lane16;
      float bcol = bias[col];
#pragma unroll
      for (int r = 0; r < 4; ++r) {
        int rowL = w * 16 + quad * 4 + r;
        Cd[(size_t)rowL * CD + col] = f2bf(acc[nt][r] + bcol);
      }
    }
  } else {
    // ------- V path -------
    int n0s = blockIdx.x * 64;
    int b = blockIdx.y;
    const float* src = y + (size_t)b * CD * ND;
    u16* Cd = Vb + (size_t)b * CD * ND;
    const u16* Wz = Wpk + (size_t)2 * WPK_M;

    {
      int u = t & 15, grp = t >> 4;
#pragma unroll
      for (int it = 0; it < 16; ++it) {
        int c = it * 16 + grp;
        const float* col = src + (size_t)c * ND + n0s;
#pragma unroll
        for (int j = 0; j < 4; ++j)
          S1[j * 16 + u][c] = f2bf(col[j * 16 + u]);
      }
    }
    __syncthreads();

    bfrag bfr8[8];
#pragma unroll
    for (int kc = 0; kc < 8; ++kc)
      bfr8[kc] = *(const bfrag*)&S1[w * 16 + lane16][kc * 32 + quad * 8];

    ffrag o[16];
#pragma unroll
    for (int i = 0; i < 16; ++i) o[i] = ffrag{0.f, 0.f, 0.f, 0.f};

#pragma unroll
    for (int kc = 0; kc < 8; ++kc) {
      const u16* base = Wz + ((size_t)kc * 16) * 512 + l * 8;
#pragma unroll
      for (int mt = 0; mt < 16; ++mt) {
        bfrag af = *(const bfrag*)(base + mt * 512);
        o[mt] = __builtin_amdgcn_mfma_f32_16x16x32_bf16(af, bfr8[kc], o[mt], 0, 0, 0);
      }
    }
    // epilogue: d = mt*16 + quad*4 + r, n = n0s + w*16 + lane16
#pragma unroll
    for (int mt = 0; mt < 16; ++mt) {
#pragma unroll
      for (int r = 0; r < 4; ++r) {
        int d = mt * 16 + quad * 4 + r;
        Cd[(size_t)d * ND + n0s + w * 16 + lane16] = f2bf(o[mt][r] + bv[d]);
      }
    }
  }
}

// ---------- flash attention, split-K, async-DMA double-buffered ----------
// Q,K: [B*N][C]; Vt: [B][C][N]. 128 q-rows/block, 4 waves x 2 m-tiles.
// One __syncthreads per K-tile. XOR-swizzled unpadded LDS (global_load_lds).
union SmemU {
  struct {
    u16 Ks[2][NK][256];   // 32,768 B  chunk^=(row&7) swizzle
    u16 Vs[2][CD][NK];    // 32,768 B  chunk^=((d>>1)&3) swizzle
    u16 Ps[8][16][40];    // 10,240 B  wave-private P staging
  } a;                     // 75,776 B
  u16 ot[CD][136];         // 69,632 B  epilogue O^T staging
};

template <int NS>
__global__ __launch_bounds__(256, 2) void k_attn(
    const u16* __restrict__ Q, const u16* __restrict__ K,
    const u16* __restrict__ Vt, u16* __restrict__ O01,
    u16* __restrict__ O23, float* __restrict__ Lpart) {
  constexpr int NIT = ND / NS / NK;
  __shared__ alignas(16) SmemU sm;
  int b = blockIdx.y, q0 = blockIdx.x * 128, z = blockIdx.z;
  int t = threadIdx.x, w = t >> 6, l = t & 63;
  int lane16 = l & 15, quad = l >> 4;
  const float scale = 0.0625f;  // 256^-0.5

  // Q frags: A-layout rows q0 + (w*2+mi)*16 + lane16
  bfrag qf[2][8];
#pragma unroll
  for (int mi = 0; mi < 2; ++mi) {
    const u16* Qrow =
        Q + ((size_t)b * ND + q0 + (w * 2 + mi) * 16 + lane16) * CD;
#pragma unroll
    for (int kc = 0; kc < 8; ++kc)
      qf[mi][kc] = *(const bfrag*)(Qrow + kc * 32 + quad * 8);
  }

  ffrag o[2][16];
#pragma unroll
  for (int mi = 0; mi < 2; ++mi)
#pragma unroll
    for (int i = 0; i < 16; ++i) o[mi][i] = ffrag{0.f, 0.f, 0.f, 0.f};
  float lsum[2][4] = {{0.f, 0.f, 0.f, 0.f}, {0.f, 0.f, 0.f, 0.f}};

  const u16* Kb = K + ((size_t)b * ND + z * (ND / NS)) * CD;
  const u16* Vb = Vt + (size_t)b * CD * ND + z * (ND / NS);

  auto stage = [&](int kt2) {
    int dbuf = kt2 & 1;
    const u16* Kt = Kb + (size_t)kt2 * NK * CD;
    const u16* Vtt = Vb + kt2 * NK;
#pragma unroll
    for (int p = 0; p < 4; ++p) {
      int r = p * 8 + w * 2 + (l >> 5);
      int j = (l & 31) ^ (r & 7);
      gload_lds(Kt + (size_t)r * CD + j * 8, &sm.a.Ks[dbuf][p * 8 + w * 2][0]);
    }
#pragma unroll
    for (int p = 0; p < 4; ++p) {
      int dd = p * 64 + w * 16 + (l >> 2);
      int j = (l & 3) ^ ((dd >> 1) & 3);
      gload_lds(Vtt + (size_t)dd * ND + j * 8, &sm.a.Vs[dbuf][p * 64 + w * 16][0]);
    }
  };

  stage(0);
  for (int kt = 0; kt < NIT; ++kt) {
    int dbuf = kt & 1;
    __syncthreads();  // drains DMA for buf dbuf; recycling of dbuf^1 is safe
    if (kt + 1 < NIT) stage(kt + 1);  // async into other buffer, no wait

    // S = Q K^T  (2 m-tiles x 2 key-tiles)
    ffrag s2[2][2];
#pragma unroll
    for (int mi = 0; mi < 2; ++mi)
#pragma unroll
      for (int tt = 0; tt < 2; ++tt) s2[mi][tt] = ffrag{0.f, 0.f, 0.f, 0.f};
#pragma unroll
    for (int kc = 0; kc < 8; ++kc) {
      bfrag kf0, kf1;
      {
        int r = lane16;
        int cp = (kc * 4 + quad) ^ (r & 7);
        kf0 = *(const bfrag*)&sm.a.Ks[dbuf][r][cp * 8];
        int r1 = 16 + lane16;
        int cp1 = (kc * 4 + quad) ^ (r1 & 7);
        kf1 = *(const bfrag*)&sm.a.Ks[dbuf][r1][cp1 * 8];
      }
#pragma unroll
      for (int mi = 0; mi < 2; ++mi) {
        s2[mi][0] = __builtin_amdgcn_mfma_f32_16x16x32_bf16(qf[mi][kc], kf0,
                                                            s2[mi][0], 0, 0, 0);
        s2[mi][1] = __builtin_amdgcn_mfma_f32_16x16x32_bf16(qf[mi][kc], kf1,
                                                            s2[mi][1], 0, 0, 0);
      }
    }

    // fixed-max softmax: p = exp(s*scale); lane-partial sums; P -> LDS
#pragma unroll
    for (int mi = 0; mi < 2; ++mi)
#pragma unroll
      for (int tt = 0; tt < 2; ++tt)
#pragma unroll
        for (int r = 0; r < 4; ++r) {
          float p = __expf(s2[mi][tt][r] * scale);
          lsum[mi][r] += p;
          sm.a.Ps[w * 2 + mi][quad * 4 + r][tt * 16 + lane16] = f2bf(p);
        }
    // wave-private Ps: in-wave LDS ordering suffices, no barrier
    bfrag pf0 = *(const bfrag*)&sm.a.Ps[w * 2 + 0][lane16][quad * 8];
    bfrag pf1 = *(const bfrag*)&sm.a.Ps[w * 2 + 1][lane16][quad * 8];

    // O += P V  (16 d-tiles, V-frag shared across both m-tiles)
#pragma unroll
    for (int dt = 0; dt < 16; ++dt) {
      int dd = dt * 16 + lane16;
      int cp = quad ^ ((dd >> 1) & 3);
      bfrag vf = *(const bfrag*)&sm.a.Vs[dbuf][dd][cp * 8];
      o[0][dt] = __builtin_amdgcn_mfma_f32_16x16x32_bf16(pf0, vf, o[0][dt], 0, 0, 0);
      o[1][dt] = __builtin_amdgcn_mfma_f32_16x16x32_bf16(pf1, vf, o[1][dt], 0, 0, 0);
    }
  }

  // row-sum reduction: 16-lane butterfly within quad groups, once
#pragma unroll
  for (int mi = 0; mi < 2; ++mi)
#pragma unroll
    for (int r = 0; r < 4; ++r) {
#pragma unroll
      for (int off = 1; off < 16; off <<= 1)
        lsum[mi][r] += __shfl_xor(lsum[mi][r], off, 64);
    }
  if (lane16 == 0) {
#pragma unroll
    for (int mi = 0; mi < 2; ++mi)
#pragma unroll
      for (int r = 0; r < 4; ++r)
        Lpart[((size_t)z * BN + b) * ND + q0 + (w * 2 + mi) * 16 + quad * 4 + r] =
            lsum[mi][r];
  }

  __syncthreads();
  // unnormalized O -> transposed bf16 staging ot[d][q_local]
#pragma unroll
  for (int mi = 0; mi < 2; ++mi)
#pragma unroll
    for (int dt = 0; dt < 16; ++dt)
#pragma unroll
      for (int r = 0; r < 4; ++r)
        sm.ot[dt * 16 + lane16][(w * 2 + mi) * 16 + quad * 4 + r] =
            f2bf(o[mi][dt][r]);
  __syncthreads();
  const size_t SZc = (size_t)BN * ND * CD;
  u16* Op = ((z < 2) ? O01 : O23) + (size_t)(z & 1) * SZc;
#pragma unroll
  for (int it = 0; it < 16; ++it) {
    int c = it * 256 + t;
    int dd = c >> 4, co = (c & 15) * 8;
    size_t g = ((size_t)b * CD + dd) * ND + q0 + co;
    *(uint4*)(Op + g) = *(const uint4*)&sm.ot[dd][co];
  }
}

// ---------- combine partials + residual ----------
template <int NS>
__global__ __launch_bounds__(256) void k_combine(
    const u16* __restrict__ O01, const u16* __restrict__ O23,
    const float* __restrict__ L, const float* __restrict__ x,
    float* __restrict__ out) {
  const size_t SZc = (size_t)BN * ND * CD;
  size_t e = ((size_t)blockIdx.x * 256 + threadIdx.x) * 8;
  int n = (int)(e & (ND - 1));
  int b = (int)(e >> 20);  // C*N = 2^20
  float ls[8] = {0, 0, 0, 0, 0, 0, 0, 0};
  float acc[8] = {0, 0, 0, 0, 0, 0, 0, 0};
#pragma unroll
  for (int z = 0; z < NS; ++z) {
    const float* Lr = L + ((size_t)z * BN + b) * ND + n;
    float4 l0 = *(const float4*)(Lr);
    float4 l1 = *(const float4*)(Lr + 4);
    ls[0] += l0.x; ls[1] += l0.y; ls[2] += l0.z; ls[3] += l0.w;
    ls[4] += l1.x; ls[5] += l1.y; ls[6] += l1.z; ls[7] += l1.w;
    const u16* Oz = ((z < 2) ? O01 : O23) + (size_t)(z & 1) * SZc + e;
    union { uint4 q; u16 s[8]; } u;
    u.q = *(const uint4*)Oz;
#pragma unroll
    for (int j = 0; j < 8; ++j) acc[j] += bf2f(u.s[j]);
  }
  float4 x0 = *(const float4*)(x + e);
  float4 x1 = *(const float4*)(x + e + 4);
  float4 r0, r1;
  r0.x = x0.x + acc[0] / ls[0];
  r0.y = x0.y + acc[1] / ls[1];
  r0.z = x0.z + acc[2] / ls[2];
  r0.w = x0.w + acc[3] / ls[3];
  r1.x = x1.x + acc[4] / ls[4];
  r1.y = x1.y + acc[5] / ls[5];
  r1.z = x1.z + acc[6] / ls[6];
  r1.w = x1.w + acc[7] / ls[7];
  *(float4*)(out + e) = r0;
  *(float4*)(out + e + 4) = r1;
}

extern "C" void kernel_launch(void* const* d_in, const int* in_sizes, int n_in,
                              void* d_out, int out_size, void* d_ws, size_t ws_size,
                              hipStream_t stream) {
  const float* x  = (const float*)d_in[0];
  const float* y  = (const float*)d_in[1];
  const float* Wq = (const float*)d_in[2];
  const float* bq = (const float*)d_in[3];
  const float* Wk = (const float*)d_in[4];
  const float* bk = (const float*)d_in[5];
  const float* Wv = (const float*)d_in[6];
  const float* bv = (const float*)d_in[7];
  float* out = (float*)d_out;
  u16* ws = (u16*)d_ws;
  const size_t SZ = (size_t)BN * ND * CD;  // 4,194,304 elems per tensor
  u16* Qb = ws;
  u16* Kb = Qb + SZ;
  u16* Vb = Kb + SZ;
  u16* Ob = Vb + SZ;  // NS partials, contiguous
  // NS=4: 7*SZ bf16 + 4*BN*ND fp32 (L) + 384 KB packed W
  const size_t need4 = 7 * SZ * sizeof(u16) +
                       (size_t)4 * BN * ND * sizeof(float) +
                       (size_t)3 * WPK_M * sizeof(u16);
  const bool big = ws_size >= need4;  // constant across calls (graph-safe)
  const int cgrid = (int)(SZ / (256 * 8));  // 2048 blocks (out = SZ floats)

  if (big) {
    float* Lp = (float*)(Ob + 4 * SZ);
    u16* Wpk = (u16*)(Lp + (size_t)4 * BN * ND);
    k_packW<<<dim3(96), 256, 0, stream>>>(Wq, Wk, Wv, Wpk);
    k_proj3<<<dim3(64, 4, 3), 256, 0, stream>>>(x, y, Wpk, bq, bk, bv,
                                                Qb, Kb, Vb);
    k_attn<4><<<dim3(ND / 128, BN, 4), 256, 0, stream>>>(Qb, Kb, Vb, Ob,
                                                         Ob + 2 * SZ, Lp);
    k_combine<4><<<dim3(cgrid), 256, 0, stream>>>(Ob, Ob + 2 * SZ, Lp, x, out);
  } else {
    float* Lp = (float*)(Ob + 2 * SZ);
    u16* Wpk = (u16*)(Lp + (size_t)2 * BN * ND);
    k_packW<<<dim3(96), 256, 0, stream>>>(Wq, Wk, Wv, Wpk);
    k_proj3<<<dim3(64, 4, 3), 256, 0, stream>>>(x, y, Wpk, bq, bk, bv,
                                                Qb, Kb, Vb);
    k_attn<2><<<dim3(ND / 128, BN, 2), 256, 0, stream>>>(Qb, Kb, Vb, Ob, Ob, Lp);
    k_combine<2><<<dim3(cgrid), 256, 0, stream>>>(Ob, Ob, Lp, x, out);
  }
}